// Round 1
// baseline (88294.067 us; speedup 1.0000x reference)
//
#include <hip/hip_runtime.h>

#define T_LEN 16384
#define NT 1024
#define NW 32        // worker blocks, all elected onto ONE XCD (32 CUs)
#define CPB 32       // columns per worker block
#define GRID 512     // candidate blocks for the election (>=256 => pigeonhole winner)
#define NTHR 256
#define SPIN_LIMIT 32

typedef unsigned long long u64;
typedef unsigned int u32;
typedef __attribute__((ext_vector_type(4))) u32 u32x4;

// ws layout (unchanged from previous kernel):
//   u64 buf0[1024] @ bytes [0,8192)      tagged alpha, even parity  (fast / sc0 path)
//   u64 buf1[1024] @ bytes [8192,16384)  tagged alpha, odd parity   (fast / sc0 path)
//   float gold     @ float index 4096
// tagged word = (step_tag << 32) | float_bits  -- tag+data fused => no fences needed.

// Device-global side channel (not in ws): guaranteed-visible mirror of the tagged
// alpha stream (agent-scope atomics -> MALL), plus election state.
__device__ __align__(32) u64 g_mirror[2 * NT];
__device__ int g_cnt[8];
__device__ int g_winner = -1;

__device__ __forceinline__ u64 pack_tag(u32 tag, float v) {
  return ((u64)tag << 32) | (u64)__float_as_uint(v);
}
__device__ __forceinline__ u64 ld_tag(const u64* p) {
  return __hip_atomic_load(p, __ATOMIC_RELAXED, __HIP_MEMORY_SCOPE_AGENT);
}
__device__ __forceinline__ void st_tag(u64* p, u64 v) {
  __hip_atomic_store(p, v, __ATOMIC_RELAXED, __HIP_MEMORY_SCOPE_AGENT);
}

// Fast path: sc0 = bypass L1, coherent at the (single, shared) XCD L2.
// 2x dwordx4 loads 4 consecutive tagged words (32B); one batched waitcnt.
__device__ __forceinline__ void ld8_sc0(const u64* q, u32x4& A, u32x4& B) {
  asm volatile("global_load_dwordx4 %0, %2, off sc0\n\t"
               "global_load_dwordx4 %1, %2, off offset:16 sc0\n\t"
               "s_waitcnt vmcnt(0)"
               : "=&v"(A), "=&v"(B)
               : "v"(q)
               : "memory");
}
__device__ __forceinline__ void st_sc0(u64* p, u64 v) {
  asm volatile("global_store_dwordx2 %0, %1, off sc0" :: "v"(p), "v"(v) : "memory");
}

__device__ __forceinline__ int xcc_id() {
  int x;
  asm volatile("s_getreg_b32 %0, hwreg(HW_REG_XCC_ID)" : "=s"(x));
  return x & 7;
}

// Guaranteed fallback: poll the MALL-visible mirror until all 4 tags are fresh.
__device__ __forceinline__ void poll_mirror(const u64* m, u32 want, u32x4& A, u32x4& B) {
  u64 w0 = ld_tag(m + 0), w1 = ld_tag(m + 1), w2 = ld_tag(m + 2), w3 = ld_tag(m + 3);
  for (;;) {
    bool s0 = (u32)(w0 >> 32) != want;
    bool s1 = (u32)(w1 >> 32) != want;
    bool s2 = (u32)(w2 >> 32) != want;
    bool s3 = (u32)(w3 >> 32) != want;
    if (!(s0 | s1 | s2 | s3)) break;
    if (s0) w0 = ld_tag(m + 0);
    if (s1) w1 = ld_tag(m + 1);
    if (s2) w2 = ld_tag(m + 2);
    if (s3) w3 = ld_tag(m + 3);
  }
  A.x = (u32)w0; A.y = (u32)(w0 >> 32);
  A.z = (u32)w1; A.w = (u32)(w1 >> 32);
  B.x = (u32)w2; B.y = (u32)(w2 >> 32);
  B.z = (u32)w3; B.w = (u32)(w3 >> 32);
}

__global__ __launch_bounds__(1024) void crf_init(const float* __restrict__ emit,
                                                 const float* __restrict__ strans,
                                                 u64* __restrict__ buf) {
  int tid = threadIdx.x;
  float a0 = strans[tid] + emit[tid];
  u64 w = pack_tag(0u, a0);
  buf[tid] = w;        // fast buffer (kernel-boundary release makes this visible)
  g_mirror[tid] = w;   // mirror buffer
  if (tid < 8) g_cnt[tid] = 0;   // reset election state every launch/replay
  if (tid == 8) g_winner = -1;
}

__global__ __launch_bounds__(1024) void crf_score(const float* __restrict__ emit,
                                                  const int* __restrict__ y,
                                                  const float* __restrict__ trans,
                                                  const float* __restrict__ strans,
                                                  const float* __restrict__ etrans,
                                                  float* __restrict__ ws) {
  int tid = threadIdx.x;
  float local = 0.f;
  for (int t = tid; t < T_LEN; t += 1024) {
    int yt = y[t];
    local += emit[t * NT + yt];
    if (t > 0) local += trans[y[t - 1] * NT + yt];
  }
  if (tid == 0) local += strans[y[0]];
  if (tid == 1023) local += etrans[y[T_LEN - 1]];
#pragma unroll
  for (int o = 32; o; o >>= 1) local += __shfl_xor(local, o);
  __shared__ float sm[16];
  if ((tid & 63) == 0) sm[tid >> 6] = local;
  __syncthreads();
  if (tid == 0) {
    float s = 0.f;
    for (int i = 0; i < 16; ++i) s += sm[i];
    ws[4096] = s;
  }
}

__global__ __launch_bounds__(NTHR, 1) void crf_scan(const float* __restrict__ emit,
                                                    const float* __restrict__ trans,
                                                    u64* buf) {
  const int tid = threadIdx.x;

  // ---- Election: first XCD to accumulate NW candidate blocks wins; its
  // candidates become workers 0..NW-1, everyone else exits. Termination is
  // guaranteed: all GRID blocks are co-schedulable, and any assignment of
  // >=256 blocks to 8 XCDs puts >=32 on some XCD.
  __shared__ int s_blk;
  if (tid == 0) {
    int role = -1;
    int xcd = xcc_id();
    int r = atomicAdd(&g_cnt[xcd], 1);
    if (r < NW) {
      if (r == NW - 1) atomicCAS(&g_winner, -1, xcd);
      int w;
      do {
        w = __hip_atomic_load(&g_winner, __ATOMIC_RELAXED, __HIP_MEMORY_SCOPE_AGENT);
      } while (w == -1);
      if (w == xcd) role = r;
    }
    s_blk = role;
  }
  __syncthreads();
  const int blk = s_blk;
  if (blk < 0) return;

  const int c = tid & 31;        // local column 0..31
  const int chunk = tid >> 5;    // j-chunk 0..7 (128 j's each)
  const int col = blk * CPB + c;
  const int wv = tid >> 6;       // wave 0..3

  u64* buf0 = buf;
  u64* buf1 = buf + NT;
  u64* mir0 = g_mirror;
  u64* mir1 = g_mirror + NT;

  // P fragment: p[i] = exp(trans[128*chunk + i, col]); one-time, fully unrolled
  // so p[] stays in VGPRs (runtime indexing would spill to scratch).
  float p[128];
  const int jb = chunk << 7;
#pragma unroll
  for (int i = 0; i < 128; ++i)
    p[i] = __expf(trans[(jb + i) * NT + col]);

  __shared__ __align__(16) float aS[NT];
  __shared__ float partS[128];   // [wave][32 cols]

  // initial block-local scale M = max over this block's 32 columns of alpha_0
  float M;
  {
    u64 wd = ld_tag(buf0 + col);
    float v = __uint_as_float((u32)wd);
#pragma unroll
    for (int o = 16; o; o >>= 1) v = fmaxf(v, __shfl_xor(v, o));
    M = v;
  }

  for (int t = 1; t < T_LEN; ++t) {
    u64* bIn  = (t & 1) ? buf0 : buf1;   // holds tag t-1
    u64* bOut = (t & 1) ? buf1 : buf0;   // receives tag t
    u64* mIn  = (t & 1) ? mir0 : mir1;
    u64* mOut = (t & 1) ? mir1 : mir0;

    float e = emit[t * NT + col];        // issued before the poll; in flight under it

    // Poll 4 contiguous tagged words per thread through the shared XCD L2.
    // Bounded spin, then fall back to the MALL mirror (always correct: tags
    // fused with data make stale or torn observations unacceptable-by-construction).
    const u32 want = (u32)(t - 1);
    u32x4 A, B;
    {
      const u64* q = bIn + (tid << 2);
      int spins = 0;
      for (;;) {
        ld8_sc0(q, A, B);
        if (!((A.y ^ want) | (A.w ^ want) | (B.y ^ want) | (B.w ^ want))) break;
        if (++spins > SPIN_LIMIT) { poll_mirror(mIn + (tid << 2), want, A, B); break; }
      }
    }
    float4 av;
    av.x = __expf(__uint_as_float(A.x) - M);
    av.y = __expf(__uint_as_float(A.z) - M);
    av.z = __expf(__uint_as_float(B.x) - M);
    av.w = __expf(__uint_as_float(B.z) - M);
    ((float4*)aS)[tid] = av;
    __syncthreads();

    // GEMV: thread owns (col c, 128-wide j-chunk): 32 broadcast float4 LDS reads,
    // 128 FMA split across 4 accumulators (dep chain ~32 FMA instead of 128).
    float sx = 0.f, sy = 0.f, sz = 0.f, sw = 0.f;
    const float4* aV = (const float4*)aS;
    const int base = chunk << 5;
#pragma unroll
    for (int i = 0; i < 32; ++i) {
      float4 a4 = aV[base + i];
      sx = fmaf(a4.x, p[4 * i + 0], sx);
      sy = fmaf(a4.y, p[4 * i + 1], sy);
      sz = fmaf(a4.z, p[4 * i + 2], sz);
      sw = fmaf(a4.w, p[4 * i + 3], sw);
    }
    float s = (sx + sy) + (sz + sw);
    s += __shfl_xor(s, 32);              // combine the wave's 2 chunks
    if ((tid & 63) < 32) partS[wv * 32 + c] = s;
    __syncthreads();

    // cross-wave combine (redundant per thread: 4 LDS reads)
    float tot = partS[c] + partS[32 + c] + partS[64 + c] + partS[96 + c];
    float anew = e + M + __logf(tot);
    if (tid < 32) {
      u64 w = pack_tag((u32)t, anew);
      st_sc0(bOut + col, w);   // fast path: stays in the winning XCD's L2
      st_tag(mOut + col, w);   // mirror: MALL-visible for fallback + crf_final
    }

    // block-local M for next step: max over this block's 32 fresh columns
    float m2 = anew;
#pragma unroll
    for (int o = 16; o; o >>= 1) m2 = fmaxf(m2, __shfl_xor(m2, o));
    M = m2;
  }
}

__global__ __launch_bounds__(1024) void crf_final(const float* __restrict__ etrans,
                                                  const float* __restrict__ ws,
                                                  float* __restrict__ out) {
  int tid = threadIdx.x;
  // final alpha (t = 16383, odd) lives in the odd mirror buffer (MALL-visible,
  // independent of any L2 writeback of the fast path).
  float v = __uint_as_float((u32)g_mirror[NT + tid]) + etrans[tid];
  float m = v;
#pragma unroll
  for (int o = 32; o; o >>= 1) m = fmaxf(m, __shfl_xor(m, o));
  __shared__ float sm[16];
  __shared__ float sM;
  if ((tid & 63) == 0) sm[tid >> 6] = m;
  __syncthreads();
  if (tid == 0) {
    float mm = sm[0];
    for (int i = 1; i < 16; ++i) mm = fmaxf(mm, sm[i]);
    sM = mm;
  }
  __syncthreads();
  float Mv = sM;
  float s = __expf(v - Mv);
#pragma unroll
  for (int o = 32; o; o >>= 1) s += __shfl_xor(s, o);
  __shared__ float ss[16];
  if ((tid & 63) == 0) ss[tid >> 6] = s;
  __syncthreads();
  if (tid == 0) {
    float tot = 0.f;
    for (int i = 0; i < 16; ++i) tot += ss[i];
    float logZ = Mv + __logf(tot);
    out[0] = logZ - ws[4096];
  }
}

extern "C" void kernel_launch(void* const* d_in, const int* in_sizes, int n_in,
                              void* d_out, int out_size, void* d_ws, size_t ws_size,
                              hipStream_t stream) {
  const float* emit = (const float*)d_in[0];
  const int* y = (const int*)d_in[1];
  const float* trans = (const float*)d_in[2];
  const float* strans = (const float*)d_in[3];
  const float* etrans = (const float*)d_in[4];
  u64* buf = (u64*)d_ws;
  float* ws = (float*)d_ws;
  float* out = (float*)d_out;

  crf_init<<<1, 1024, 0, stream>>>(emit, strans, buf);
  crf_score<<<1, 1024, 0, stream>>>(emit, y, trans, strans, etrans, ws);
  crf_scan<<<GRID, NTHR, 0, stream>>>(emit, trans, buf);
  crf_final<<<1, 1024, 0, stream>>>(etrans, ws, out);
}

// Round 2
// 15178.459 us; speedup vs baseline: 5.8171x; 5.8171x over previous
//
#include <hip/hip_runtime.h>

#define T_LEN 16384
#define NT 1024
#define NBLK 64      // blocks per direction (x2 directions)
#define CPB 16       // columns (fwd) / rows (bwd) per block
#define NTHR 256     // 4 waves
#define MID 8191     // forward computes alpha_MID (8191 steps); backward beta_MID (8192 steps)

typedef unsigned long long u64;
typedef unsigned int u32;

// Exchange buffers as device globals (proven-equivalent memory type in R1).
// g_fbuf: [0..NT) even-parity tags, [NT..2NT) odd-parity tags — forward alpha.
// g_bbuf: same layout — backward (beta_t + emit[t,:]) stream.
// tagged word = (step_tag << 32) | float_bits; tag+data fused => no fences needed.
// Zero-init safety: odd-parity halves start tag=0, but odd buffers only ever
// await odd tags. Even halves are rewritten by crf_init before crf_scan.
__device__ __align__(16) u64 g_fbuf[2 * NT];
__device__ __align__(16) u64 g_bbuf[2 * NT];

__device__ __forceinline__ u64 pack_tag(u32 tag, float v) {
  return ((u64)tag << 32) | (u64)__float_as_uint(v);
}
__device__ __forceinline__ u64 ld_tag(const u64* p) {
  return __hip_atomic_load(p, __ATOMIC_RELAXED, __HIP_MEMORY_SCOPE_AGENT);
}
__device__ __forceinline__ void st_tag(u64* p, u64 v) {
  __hip_atomic_store(p, v, __ATOMIC_RELAXED, __HIP_MEMORY_SCOPE_AGENT);
}

__global__ __launch_bounds__(1024) void crf_init(const float* __restrict__ emit,
                                                 const float* __restrict__ strans,
                                                 const float* __restrict__ etrans) {
  int tid = threadIdx.x;
  // forward seed: alpha_0 = strans + emit[0,:]
  g_fbuf[tid] = pack_tag(0u, strans[tid] + emit[tid]);
  // backward seed: stored_0[k] = beta_{T-1}[k] + emit[T-1,k] = etrans[k] + emit[T-1,k]
  g_bbuf[tid] = pack_tag(0u, etrans[tid] + emit[(T_LEN - 1) * NT + tid]);
}

__global__ __launch_bounds__(1024) void crf_score(const float* __restrict__ emit,
                                                  const int* __restrict__ y,
                                                  const float* __restrict__ trans,
                                                  const float* __restrict__ strans,
                                                  const float* __restrict__ etrans,
                                                  float* __restrict__ ws) {
  int tid = threadIdx.x;
  float local = 0.f;
  for (int t = tid; t < T_LEN; t += 1024) {
    int yt = y[t];
    local += emit[t * NT + yt];
    if (t > 0) local += trans[y[t - 1] * NT + yt];
  }
  if (tid == 0) local += strans[y[0]];
  if (tid == 1023) local += etrans[y[T_LEN - 1]];
#pragma unroll
  for (int o = 32; o; o >>= 1) local += __shfl_xor(local, o);
  __shared__ float sm[16];
  if ((tid & 63) == 0) sm[tid >> 6] = local;
  __syncthreads();
  if (tid == 0) {
    float s = 0.f;
    for (int i = 0; i < 16; ++i) s += sm[i];
    ws[4096] = s;
  }
}

// Blocks [0,64): forward chain. Blocks [64,128): backward chain.
// Per-step body is identical for both directions (verified 24.8ms schedule);
// only the trans orientation, emit row index, and buffer set differ.
__global__ __launch_bounds__(NTHR, 1) void crf_scan(const float* __restrict__ emit,
                                                    const float* __restrict__ trans) {
  const int tid = threadIdx.x;
  const bool fwd = blockIdx.x < NBLK;
  const int blk = fwd ? blockIdx.x : (blockIdx.x - NBLK);

  const int c = tid & 15;        // local column (fwd) / row (bwd)
  const int chunk = tid >> 4;    // reduction-dim chunk 0..15 (64 each)
  const int col = blk * CPB + c;
  const int wv = tid >> 6;       // wave 0..3

  u64* buf0 = fwd ? g_fbuf : g_bbuf;
  u64* buf1 = buf0 + NT;
  const int STEPS = fwd ? MID : (T_LEN - 1 - MID);   // 8191 / 8192

  // P fragment: fwd: p = exp(trans[j, col]) (column of trans);
  //             bwd: p = exp(trans[col, k]) (row of trans, coalesced).
  // The 8*chunk stagger keeps the 4 distinct LDS lines per wave-read on
  // disjoint bank quads -> conflict-free broadcast reads (unchanged).
  float p[64];
  const int jbase = chunk * 64;
#pragma unroll
  for (int i = 0; i < 16; ++i) {
    int off = (4 * i + 8 * chunk) & 63;
#pragma unroll
    for (int x = 0; x < 4; ++x) {
      int jj = jbase + off + x;
      float tv = fwd ? trans[jj * NT + col] : trans[col * NT + jj];
      p[4 * i + x] = __expf(tv);
    }
  }

  __shared__ __align__(16) float aS[NT];
  __shared__ float partS[64];    // [wave][16 cols]

  // initial block-local scale M = max over this block's 16 seed values
  float M;
  {
    u64 wd = ld_tag(buf0 + col);
    float v = __uint_as_float((u32)wd);
#pragma unroll
    for (int o = 8; o; o >>= 1) v = fmaxf(v, __shfl_xor(v, o));
    M = v;
  }

  const int i0 = tid, i1 = tid + 256, i2 = tid + 512, i3 = tid + 768;

  for (int n = 1; n <= STEPS; ++n) {
    u64* bIn  = (n & 1) ? buf0 : buf1;   // holds tag n-1
    u64* bOut = (n & 1) ? buf1 : buf0;   // receives tag n

    const int te = fwd ? n : (T_LEN - 1 - n);
    float e = emit[te * NT + col];       // in flight during the poll below

    // poll 4 tagged words per thread, kept independently in flight (known-good)
    const u32 want = (u32)(n - 1);
    u64 w0 = ld_tag(bIn + i0), w1 = ld_tag(bIn + i1);
    u64 w2 = ld_tag(bIn + i2), w3 = ld_tag(bIn + i3);
    for (;;) {
      bool s0 = (u32)(w0 >> 32) != want;
      bool s1 = (u32)(w1 >> 32) != want;
      bool s2 = (u32)(w2 >> 32) != want;
      bool s3 = (u32)(w3 >> 32) != want;
      if (!(s0 | s1 | s2 | s3)) break;
      if (s0) w0 = ld_tag(bIn + i0);
      if (s1) w1 = ld_tag(bIn + i1);
      if (s2) w2 = ld_tag(bIn + i2);
      if (s3) w3 = ld_tag(bIn + i3);
    }
    aS[i0] = __expf(__uint_as_float((u32)w0) - M);
    aS[i1] = __expf(__uint_as_float((u32)w1) - M);
    aS[i2] = __expf(__uint_as_float((u32)w2) - M);
    aS[i3] = __expf(__uint_as_float((u32)w3) - M);
    __syncthreads();

    // GEMV: thread owns (c, chunk): 16 broadcast float4 reads + 64 FMA
    float s = 0.f;
    const float4* aV = (const float4*)aS;
#pragma unroll
    for (int i = 0; i < 16; ++i) {
      int off = (4 * i + 8 * chunk) & 63;
      float4 a4 = aV[(jbase + off) >> 2];
      s = fmaf(a4.x, p[4 * i + 0], s);
      s = fmaf(a4.y, p[4 * i + 1], s);
      s = fmaf(a4.z, p[4 * i + 2], s);
      s = fmaf(a4.w, p[4 * i + 3], s);
    }
    // reduce over the wave's 4 chunks (tid bits 4,5)
    s += __shfl_xor(s, 16);
    s += __shfl_xor(s, 32);
    if ((tid & 63) < 16) partS[wv * 16 + c] = s;
    __syncthreads();

    // final cross-wave combine, done redundantly by every thread (4 LDS reads)
    float tot = partS[c] + partS[16 + c] + partS[32 + c] + partS[48 + c];
    // fwd: anew = alpha_n[col];  bwd: anew = beta_t[col] + emit[t,col]
    // (identical expression: e + M + log(tot))
    float anew = e + M + __logf(tot);
    if (tid < 16) st_tag(bOut + col, pack_tag((u32)n, anew));

    // block-local M for next step: max over this block's 16 fresh values
    float m2 = anew;
#pragma unroll
    for (int o = 8; o; o >>= 1) m2 = fmaxf(m2, __shfl_xor(m2, o));
    M = m2;
  }
}

__global__ __launch_bounds__(1024) void crf_final(const float* __restrict__ emit,
                                                  const float* __restrict__ ws,
                                                  float* __restrict__ out) {
  int tid = threadIdx.x;
  // alpha_MID: tag 8191 (odd) -> g_fbuf odd half.
  // beta-stream tag 8192 (even) -> g_bbuf even half; stored = beta_MID + emit[MID,:].
  float fa = __uint_as_float((u32)g_fbuf[NT + tid]);
  float bb = __uint_as_float((u32)g_bbuf[tid]);
  float v = fa + bb - emit[MID * NT + tid];   // alpha_MID + beta_MID
  float m = v;
#pragma unroll
  for (int o = 32; o; o >>= 1) m = fmaxf(m, __shfl_xor(m, o));
  __shared__ float sm[16];
  __shared__ float sM;
  if ((tid & 63) == 0) sm[tid >> 6] = m;
  __syncthreads();
  if (tid == 0) {
    float mm = sm[0];
    for (int i = 1; i < 16; ++i) mm = fmaxf(mm, sm[i]);
    sM = mm;
  }
  __syncthreads();
  float Mv = sM;
  float s = __expf(v - Mv);
#pragma unroll
  for (int o = 32; o; o >>= 1) s += __shfl_xor(s, o);
  __shared__ float ss[16];
  if ((tid & 63) == 0) ss[tid >> 6] = s;
  __syncthreads();
  if (tid == 0) {
    float tot = 0.f;
    for (int i = 0; i < 16; ++i) tot += ss[i];
    float logZ = Mv + __logf(tot);
    out[0] = logZ - ws[4096];
  }
}

extern "C" void kernel_launch(void* const* d_in, const int* in_sizes, int n_in,
                              void* d_out, int out_size, void* d_ws, size_t ws_size,
                              hipStream_t stream) {
  const float* emit = (const float*)d_in[0];
  const int* y = (const int*)d_in[1];
  const float* trans = (const float*)d_in[2];
  const float* strans = (const float*)d_in[3];
  const float* etrans = (const float*)d_in[4];
  float* ws = (float*)d_ws;
  float* out = (float*)d_out;

  crf_init<<<1, 1024, 0, stream>>>(emit, strans, etrans);
  crf_score<<<1, 1024, 0, stream>>>(emit, y, trans, strans, etrans, ws);
  crf_scan<<<2 * NBLK, NTHR, 0, stream>>>(emit, trans);
  crf_final<<<1, 1024, 0, stream>>>(emit, ws, out);
}